// Round 15
// baseline (15734.045 us; speedup 1.0000x reference)
//
#include <hip/hip_runtime.h>
#include <hip/hip_fp8.h>
#include <math.h>

// SimpleNeuroSAT on MI355X — round 14: round-13 base + (1) LDS-staged lofs
// window in c_update (kills the lofs->gather dependent chain level; safe
// version of round-9's failed register hoisting) + (2) LDS bank-conflict
// padding SK 168->170, 264->266 (gcd with 32 banks -> 1).
// MFMA 16x16x32_bf16: A[m=lane&15][k=quad*8+j]; B[k=quad*8+j][n=lane&15];
// D: col=lane&15, row=quad*4+reg (HW-verified m89/m91/m120).
// State: Cb bf16 (direct) + Cb8 fp8 (gather); Lraw bf16; Lb bf16 + Lb8 fp8
// pre-normed [v|v+nv]; CLb bf16 messages. slab stats as before.

#define NROUNDS 32
#define NORM_EPS 1e-3f
#define LOSS_EPS 1e-8f

static constexpr int NV_CONST = 100000;
static constexpr int NG_CONST = 100;

typedef __attribute__((ext_vector_type(8))) short short8;
typedef __attribute__((ext_vector_type(8))) unsigned char uchar8;
typedef __attribute__((ext_vector_type(16))) unsigned char uchar16;
typedef __attribute__((ext_vector_type(4))) float f32x4;

__device__ __forceinline__ short f2bf(float f) {
    union { float f; unsigned u; } x; x.f = f;
    unsigned r = x.u + 0x7fffu + ((x.u >> 16) & 1u);   // RNE
    return (short)(r >> 16);
}
__device__ __forceinline__ float bf2f(short s) {
    union { unsigned u; float f; } x; x.u = ((unsigned)(unsigned short)s) << 16;
    return x.f;
}
__device__ __forceinline__ unsigned char f2q8(float f) {
    f = fminf(fmaxf(f, -448.f), 448.f);    // e4m3fn finite range
    __hip_fp8_e4m3 t(f);
    return t.__x;
}
__device__ __forceinline__ float q82f(unsigned char b) {
    __hip_fp8_e4m3 t; t.__x = b;
    return (float)t;
}

// ---------------- setup kernels ----------------

__global__ void k_zero_i(int* __restrict__ p, int n) {
    int i = blockIdx.x * 256 + threadIdx.x;
    if (i < n) p[i] = 0;
}
__global__ void k_fill_b(short* __restrict__ p, int n, const float* __restrict__ vp) {
    int i = blockIdx.x * 256 + threadIdx.x;
    if (i < n) p[i] = f2bf(*vp);
}
__global__ void k_fill_q8(unsigned char* __restrict__ p, int n, const float* __restrict__ vp) {
    int i = blockIdx.x * 256 + threadIdx.x;
    if (i < n) p[i] = f2q8(*vp);
}
__global__ void k_copy_int(int* __restrict__ dst, const int* __restrict__ src, int n) {
    int i = blockIdx.x * 256 + threadIdx.x;
    if (i < n) dst[i] = src[i];
}
// zero all slabs; slabC[0] = identity (mean 0, E[x^2]=ncl*(1-eps) so rstd==1 exactly)
__global__ void k_init_slabs(float* __restrict__ slabC, float* __restrict__ slabL,
                             float* __restrict__ loss_a, float nclf) {
    int i = blockIdx.x * 256 + threadIdx.x;
    if (i < 33 * 160) {
        slabC[i] = (i >= 80 && i < 160) ? nclf * (1.f - NORM_EPS) : 0.f;
        slabL[i] = 0.f;
    }
    if (i == 0) loss_a[0] = 0.f;
}

// litrow for CSR build + static chunk-offsets (8-elem units; always even, so
// the 16-elem uchar16 offset is lofs>>1)
__global__ void k_litrow(const int* __restrict__ lit_var, const int* __restrict__ lit_neg,
                         int* __restrict__ litrow, int* __restrict__ lofs,
                         int* __restrict__ counts, int ncell, int nv) {
    int i = blockIdx.x * 256 + threadIdx.x;
    if (i < ncell) {
        int r = lit_var[i] + lit_neg[i] * nv;
        litrow[i] = r;
        lofs[i] = (r < nv) ? r * 20 : (r - nv) * 20 + 10;
        atomicAdd(&counts[r], 1);
    }
}

__launch_bounds__(1024)
__global__ void k_scan4(const int* __restrict__ counts, int* __restrict__ row_ptr,
                        int n, int total) {
    __shared__ int sd[1024];
    __shared__ int carry;
    int tid = threadIdx.x;
    if (tid == 0) carry = 0;
    __syncthreads();
    for (int base = 0; base < n; base += 4096) {
        int i0 = base + tid * 4;
        int a0 = (i0 + 0 < n) ? counts[i0 + 0] : 0;
        int a1 = (i0 + 1 < n) ? counts[i0 + 1] : 0;
        int a2 = (i0 + 2 < n) ? counts[i0 + 2] : 0;
        int a3 = (i0 + 3 < n) ? counts[i0 + 3] : 0;
        int s = a0 + a1 + a2 + a3;
        sd[tid] = s;
        __syncthreads();
        for (int off = 1; off < 1024; off <<= 1) {
            int t = (tid >= off) ? sd[tid - off] : 0;
            __syncthreads();
            sd[tid] += t;
            __syncthreads();
        }
        int excl = carry + sd[tid] - s;
        if (i0 + 0 < n) row_ptr[i0 + 0] = excl;
        if (i0 + 1 < n) row_ptr[i0 + 1] = excl + a0;
        if (i0 + 2 < n) row_ptr[i0 + 2] = excl + a0 + a1;
        if (i0 + 3 < n) row_ptr[i0 + 3] = excl + a0 + a1 + a2;
        __syncthreads();
        if (tid == 0) carry += sd[1023];
        __syncthreads();
    }
    if (tid == 0) row_ptr[n] = total;
}

__global__ void k_fill_csr(const int* __restrict__ litrow, const int* __restrict__ clause_idx,
                           int* __restrict__ cursor, int* __restrict__ cl_of, int ncell) {
    int i = blockIdx.x * 256 + threadIdx.x;
    if (i < ncell) {
        int r = litrow[i];
        int pos = atomicAdd(&cursor[r], 1);
        cl_of[pos] = clause_idx[i];
    }
}

// Wp frag t=(nb*KB+kb)*64+lane holds W[kb*32+quad*8+j][nb*16+(lane&15)], zero-padded.
__global__ void k_pack_w(const float* __restrict__ W, short* __restrict__ Wp,
                         int K, int N, int KB, int NB) {
    int t = blockIdx.x * 256 + threadIdx.x;
    int tot = NB * KB * 64;
    if (t >= tot) return;
    int lane = t & 63;
    int kb = (t >> 6) % KB;
    int nb = t / (64 * KB);
    int quad = lane >> 4, l15 = lane & 15;
    int n = nb * 16 + l15;
#pragma unroll
    for (int j = 0; j < 8; ++j) {
        int k = kb * 32 + quad * 8 + j;
        float f = (k < K && n < N) ? W[(size_t)k * N + n] : 0.f;
        Wp[(size_t)t * 8 + j] = f2bf(f);
    }
}

// ---------------- MFMA building blocks ----------------

template <int KB, int NB>
__device__ __forceinline__ void mfma_layer(const short* lds, int SK,
                                           const short8* __restrict__ Wp,
                                           f32x4* acc, int lane, int arow) {
    const int quad8 = (lane >> 4) * 8;
    short8 a[KB];
#pragma unroll
    for (int kb = 0; kb < KB; ++kb)
        a[kb] = *(const short8*)(lds + arow * SK + kb * 32 + quad8);
#pragma unroll
    for (int kb = 0; kb < KB; ++kb)
#pragma unroll
        for (int nb = 0; nb < NB; ++nb)
            acc[nb] = __builtin_amdgcn_mfma_f32_16x16x32_bf16(
                a[kb], Wp[(nb * KB + kb) * 64 + lane], acc[nb], 0, 0, 0);
}

// wave-private: writes only rows wr0..wr0+15 (same stripe the wave reads)
template <int NB>
__device__ __forceinline__ void write_hidden(short* ldsH, int SKH, const f32x4* acc,
                                             const float* __restrict__ bias,
                                             int l15, int quad, int wr0) {
#pragma unroll
    for (int nb = 0; nb < NB; ++nb) {
        int c = nb * 16 + l15;
        float bv = bias[c];
#pragma unroll
        for (int reg = 0; reg < 4; ++reg) {
            int row = wr0 + quad * 4 + reg;
            float v = acc[nb][reg] + bv;
            v = fminf(fmaxf(v, 0.f), 6.f);
            ldsH[row * SKH + c] = f2bf(v);
        }
    }
}

// compute mean/rstd from an accum slab into shared sS[160] (callers sync after)
__device__ __forceinline__ void load_stats(const float* __restrict__ slab, float Minv,
                                           float* sS, int tid) {
    if (tid < 80) {
        float m = slab[tid] * Minv;
        float v = slab[80 + tid] * Minv - m * m;
        sS[tid] = m;
        sS[80 + tid] = rsqrtf(v + NORM_EPS);
    }
}

// ---------------- fused C update (LDS-staged lofs, 16B fp8 LC gather) ----------------
__launch_bounds__(256, 2)
__global__ void k_c_update(short* __restrict__ Cb, unsigned char* __restrict__ Cb8,
                           const unsigned char* __restrict__ Lb8,
                           const int* __restrict__ lofs, const float* __restrict__ scp,
                           const short8* __restrict__ W0p, const float* __restrict__ b0,
                           const short8* __restrict__ W1p, const float* __restrict__ b1,
                           const float* __restrict__ prevSlab, float* __restrict__ nextSlab,
                           float Minv, int ncl) {
    constexpr int SK = 170;                   // 85 dwords: gcd(85,32)=1, conflict-free
    __shared__ short lds[64 * SK];
    __shared__ float sred[160], sC[160];
    __shared__ int slofs[192];
    const int lane = threadIdx.x, wy = threadIdx.y, tid = wy * 64 + lane;
    const int r0 = blockIdx.x * 64;
    const int rows = (ncl - r0 < 64) ? (ncl - r0) : 64;

    if (tid < 160) sred[tid] = 0.f;
    load_stats(prevSlab, Minv, sC, tid);
    if (tid < 192) {                          // coalesced preload of this block's offsets
        int gi = r0 * 3 + tid;
        int lim = ncl * 3 - 1;
        slofs[tid] = lofs[(gi < lim) ? gi : lim] >> 1;   // uchar16-chunk offset
    }
    __syncthreads();

    const float s = *scp;
    const short8* Cbv = (const short8*)Cb;
    const uchar16* Lq = (const uchar16*)Lb8;
    // 15 items/row: 10 direct bf16 8-elem chunks + 5 gather fp8 16-elem chunks.
    // Gather offsets come from LDS (no dependent global chain).
    for (int it = tid; it < 64 * 15; it += 256) {
        int lr = it / 15, c = it - lr * 15;
        int clr = (lr < rows) ? lr : rows - 1;
        if (c < 10) {
            short8 v = Cbv[(size_t)(r0 + clr) * 10 + c];
            int col = c * 8;
            short8 o;
#pragma unroll
            for (int j = 0; j < 8; ++j)
                o[j] = f2bf((bf2f(v[j]) - sC[col + j]) * sC[80 + col + j]);
            *(short8*)(lds + lr * SK + col) = o;
        } else {
            int cc = c - 10, b = clr * 3;      // cc: 16-elem chunk 0..4
            int oa = slofs[b], ob = slofs[b + 1], oc = slofs[b + 2];
            uchar16 va = Lq[(size_t)oa + cc];
            uchar16 vb = Lq[(size_t)ob + cc];
            uchar16 vc = Lq[(size_t)oc + cc];
            short8 o0, o1;
#pragma unroll
            for (int j = 0; j < 8; ++j) {
                o0[j] = f2bf((q82f(va[j]) + q82f(vb[j]) + q82f(vc[j])) * s);
                o1[j] = f2bf((q82f(va[8 + j]) + q82f(vb[8 + j]) + q82f(vc[8 + j])) * s);
            }
            *(short8*)(lds + lr * SK + 80 + cc * 16) = o0;
            *(short8*)(lds + lr * SK + 80 + cc * 16 + 8) = o1;
        }
    }
    __syncthreads();   // staging crosses stripes; everything after is wave-private

    const int quad = lane >> 4, l15 = lane & 15, wr0 = wy * 16, arow = wr0 + l15;

    f32x4 acc[10];
#pragma unroll
    for (int nb = 0; nb < 10; ++nb) { f32x4 z = {0.f, 0.f, 0.f, 0.f}; acc[nb] = z; }
    mfma_layer<5, 10>(lds, SK, W0p, acc, lane, arow);
    write_hidden<10>(lds, SK, acc, b0, l15, quad, wr0);

    f32x4 acc2[5];
#pragma unroll
    for (int nb = 0; nb < 5; ++nb) { f32x4 z = {0.f, 0.f, 0.f, 0.f}; acc2[nb] = z; }
    mfma_layer<5, 5>(lds, SK, W1p, acc2, lane, arow);

#pragma unroll
    for (int nb = 0; nb < 5; ++nb) {
        int cc = nb * 16 + l15;
        float bv = b1[cc];
        float s1 = 0.f, s2 = 0.f;
#pragma unroll
        for (int reg = 0; reg < 4; ++reg) {
            int lr = wr0 + quad * 4 + reg;
            if (lr < rows) {
                float v = acc2[nb][reg] + bv;
                Cb[(size_t)(r0 + lr) * 80 + cc] = f2bf(v);
                Cb8[(size_t)(r0 + lr) * 80 + cc] = f2q8(v);
                s1 += v; s2 += v * v;
            }
        }
        s1 += __shfl_xor(s1, 16); s1 += __shfl_xor(s1, 32);
        s2 += __shfl_xor(s2, 16); s2 += __shfl_xor(s2, 32);
        if (quad == 0) { atomicAdd(&sred[cc], s1); atomicAdd(&sred[80 + cc], s2); }
    }
    __syncthreads();
    if (tid < 160) atomicAdd(&nextSlab[tid], sred[tid]);
}

// ---------------- standalone CL gather (fp8 source, 16B chunks, 4-unroll) ----------------
// thread = (literal row, 16-elem chunk of 5). Writes CLb = normalized bf16 message.
__launch_bounds__(256)
__global__ void k_cl_gather(const unsigned char* __restrict__ Cb8,
                            const int* __restrict__ row_ptr,
                            const int* __restrict__ cl_of, const float* __restrict__ scp,
                            const float* __restrict__ slab, float Minv,
                            short* __restrict__ CLb, int nl) {
    __shared__ float sC[160];
    load_stats(slab, Minv, sC, threadIdx.x);
    __syncthreads();
    int idx = blockIdx.x * 256 + threadIdx.x;
    if (idx >= nl * 5) return;
    int r = idx / 5, c16 = idx - r * 5;
    int p0 = row_ptr[r], p1 = row_ptr[r + 1];
    float a[16];
#pragma unroll
    for (int j = 0; j < 16; ++j) a[j] = 0.f;
    const uchar16* Cq = (const uchar16*)Cb8;
    int p = p0;
    for (; p + 4 <= p1; p += 4) {
        int i0 = cl_of[p], i1 = cl_of[p + 1], i2 = cl_of[p + 2], i3 = cl_of[p + 3];
        uchar16 v0 = Cq[(size_t)i0 * 5 + c16];
        uchar16 v1 = Cq[(size_t)i1 * 5 + c16];
        uchar16 v2 = Cq[(size_t)i2 * 5 + c16];
        uchar16 v3 = Cq[(size_t)i3 * 5 + c16];
#pragma unroll
        for (int j = 0; j < 16; ++j)
            a[j] += (q82f(v0[j]) + q82f(v1[j])) + (q82f(v2[j]) + q82f(v3[j]));
    }
    for (; p < p1; ++p) {
        uchar16 v = Cq[(size_t)cl_of[p] * 5 + c16];
#pragma unroll
        for (int j = 0; j < 16; ++j) a[j] += q82f(v[j]);
    }
    float n = (float)(p1 - p0), s = *scp;
    int col = c16 * 16;
    short8 o0, o1;
#pragma unroll
    for (int j = 0; j < 8; ++j) {
        o0[j] = f2bf((a[j] - n * sC[col + j]) * sC[80 + col + j] * s);
        o1[j] = f2bf((a[8 + j] - n * sC[col + 8 + j]) * sC[80 + col + 8 + j] * s);
    }
    ((short8*)CLb)[(size_t)r * 10 + c16 * 2] = o0;
    ((short8*)CLb)[(size_t)r * 10 + c16 * 2 + 1] = o1;
}

// ---------------- fused L update (pure streaming, ILP staging) ----------------
// paired rows [vb,vb+32) u [vb+nv,vb+nv+32); writes Lraw bf16 + accumL slab.
__launch_bounds__(256, 2)
__global__ void k_l_update(short* __restrict__ Lraw, const short* __restrict__ Lb,
                           const short* __restrict__ CLb,
                           const short8* __restrict__ W0p, const float* __restrict__ b0,
                           const short8* __restrict__ W1p, const float* __restrict__ b1,
                           float* __restrict__ nextSlab, int nv) {
    constexpr int SK = 266;                   // 133 dwords: gcd(133,32)=1
    __shared__ short lds[64 * SK];            // input K=256, then hidden 240+16pad
    __shared__ float sred[160];
    const int lane = threadIdx.x, wy = threadIdx.y, tid = wy * 64 + lane;
    const int vb = blockIdx.x * 32;

    if (tid < 160) sred[tid] = 0.f;
    __syncthreads();

    const short8* Lb8  = (const short8*)Lb;
    const short8* CLb8 = (const short8*)CLb;
    short8 vals[8];
#pragma unroll
    for (int u = 0; u < 8; ++u) {
        int it = tid + u * 256;
        int lr = it >> 5, c = it & 31;
        int v = (lr < 32) ? vb + lr : vb + (lr - 32);
        int half0 = (lr < 32) ? 0 : 10;
        if (c < 10) {
            vals[u] = Lb8[(size_t)v * 20 + half0 + c];
        } else if (c < 20) {
            int r = (lr < 32) ? vb + lr : vb + nv + (lr - 32);
            vals[u] = CLb8[(size_t)r * 10 + (c - 10)];
        } else if (c < 30) {
            vals[u] = Lb8[(size_t)v * 20 + (10 - half0) + (c - 20)];
        } else {
            short8 z = {0, 0, 0, 0, 0, 0, 0, 0};
            vals[u] = z;
        }
    }
#pragma unroll
    for (int u = 0; u < 8; ++u) {
        int it = tid + u * 256;
        int lr = it >> 5, c = it & 31;
        int o = (c < 10) ? c * 8 : (c < 20) ? 80 + (c - 10) * 8
              : (c < 30) ? 160 + (c - 20) * 8 : 240 + (c - 30) * 8;
        *(short8*)(lds + lr * SK + o) = vals[u];
    }
    __syncthreads();   // staging crosses stripes; rest is wave-private

    const int quad = lane >> 4, l15 = lane & 15, wr0 = wy * 16, arow = wr0 + l15;

    f32x4 acc[15];
#pragma unroll
    for (int nb = 0; nb < 15; ++nb) { f32x4 z = {0.f, 0.f, 0.f, 0.f}; acc[nb] = z; }
    mfma_layer<8, 15>(lds, SK, W0p, acc, lane, arow);
    write_hidden<15>(lds, SK, acc, b0, l15, quad, wr0);
    {   // zero-pad hidden cols 240..255 of OWN stripe (wave-private)
        int row = wr0 + (lane >> 2);
        int c = 240 + (lane & 3) * 4;
        short4 z; z.x = 0; z.y = 0; z.z = 0; z.w = 0;
        *(short4*)(lds + row * SK + c) = z;
    }

    f32x4 acc2[5];
#pragma unroll
    for (int nb = 0; nb < 5; ++nb) { f32x4 z = {0.f, 0.f, 0.f, 0.f}; acc2[nb] = z; }
    mfma_layer<8, 5>(lds, SK, W1p, acc2, lane, arow);

#pragma unroll
    for (int nb = 0; nb < 5; ++nb) {
        int cc = nb * 16 + l15;
        float bv = b1[cc];
        float s1 = 0.f, s2 = 0.f;
#pragma unroll
        for (int reg = 0; reg < 4; ++reg) {
            int lr = wr0 + quad * 4 + reg;
            int rabs = (lr < 32) ? vb + lr : vb + nv + (lr - 32);
            float v = acc2[nb][reg] + bv;
            Lraw[(size_t)rabs * 80 + cc] = f2bf(v);
            s1 += v; s2 += v * v;
        }
        s1 += __shfl_xor(s1, 16); s1 += __shfl_xor(s1, 32);
        s2 += __shfl_xor(s2, 16); s2 += __shfl_xor(s2, 32);
        if (quad == 0) { atomicAdd(&sred[cc], s1); atomicAdd(&sred[80 + cc], s2); }
    }
    __syncthreads();
    if (tid < 160) atomicAdd(&nextSlab[tid], sred[tid]);
}

// ---------------- fused V head (4 layers; emits Lb bf16 + Lb8 fp8) ----------------
__launch_bounds__(256, 2)
__global__ void k_v_head(const short* __restrict__ Lraw, const float* __restrict__ slab,
                         float Minv,
                         const short8* __restrict__ W0p, const float* __restrict__ b0,
                         const short8* __restrict__ W1p, const float* __restrict__ b1,
                         const short8* __restrict__ W2p, const float* __restrict__ b2,
                         const float* __restrict__ W3, const float* __restrict__ b3,
                         float* __restrict__ logits, short* __restrict__ Lb,
                         unsigned char* __restrict__ Lb8, int nv) {
    constexpr int SK = 170;                   // conflict-free stride
    __shared__ short lds[64 * SK];
    __shared__ float sW3[160], sL[160];
    const int lane = threadIdx.x, wy = threadIdx.y, tid = wy * 64 + lane;
    const int v0 = blockIdx.x * 64;
    const int cnt = (nv - v0 < 64) ? (nv - v0) : 64;

    if (tid < 160) sW3[tid] = W3[tid];
    load_stats(slab, Minv, sL, tid);
    __syncthreads();

    const short8* Lraw8 = (const short8*)Lraw;
    short8 vals[5];
#pragma unroll
    for (int u = 0; u < 5; ++u) {
        int it = tid + u * 256;
        int lr = it / 20, c = it - lr * 20;
        int v = v0 + ((lr < cnt) ? lr : cnt - 1);
        int row = (c < 10) ? v : v + nv;
        int cc = (c < 10) ? c : c - 10;
        vals[u] = Lraw8[(size_t)row * 10 + cc];
    }
#pragma unroll
    for (int u = 0; u < 5; ++u) {
        int it = tid + u * 256;
        int lr = it / 20, c = it - lr * 20;
        int v = v0 + ((lr < cnt) ? lr : cnt - 1);
        int cc = (c < 10) ? c : c - 10;
        int col = cc * 8;
        short8 o;
        uchar8 q;
#pragma unroll
        for (int j = 0; j < 8; ++j) {
            float f = (bf2f(vals[u][j]) - sL[col + j]) * sL[80 + col + j];
            o[j] = f2bf(f);
            q[j] = f2q8(f);
        }
        *(short8*)(lds + lr * SK + c * 8) = o;
        if (lr < cnt) {
            *(short8*)(Lb + (size_t)v * 160 + c * 8) = o;
            *(uchar8*)(Lb8 + (size_t)v * 160 + c * 8) = q;
        }
    }
    __syncthreads();   // staging crosses stripes

    const int quad = lane >> 4, l15 = lane & 15, wr0 = wy * 16, arow = wr0 + l15;

    f32x4 acc[10];
#pragma unroll
    for (int nb = 0; nb < 10; ++nb) { f32x4 z = {0.f, 0.f, 0.f, 0.f}; acc[nb] = z; }
    mfma_layer<5, 10>(lds, SK, W0p, acc, lane, arow);
    write_hidden<10>(lds, SK, acc, b0, l15, quad, wr0);

#pragma unroll
    for (int nb = 0; nb < 10; ++nb) { f32x4 z = {0.f, 0.f, 0.f, 0.f}; acc[nb] = z; }
    mfma_layer<5, 10>(lds, SK, W1p, acc, lane, arow);
    write_hidden<10>(lds, SK, acc, b1, l15, quad, wr0);

#pragma unroll
    for (int nb = 0; nb < 10; ++nb) { f32x4 z = {0.f, 0.f, 0.f, 0.f}; acc[nb] = z; }
    mfma_layer<5, 10>(lds, SK, W2p, acc, lane, arow);
    write_hidden<10>(lds, SK, acc, b2, l15, quad, wr0);
    __syncthreads();   // final dot reads across stripes

    int lrow = tid >> 2, t4 = tid & 3;
    float v = 0.f;
    for (int c = t4; c < 160; c += 4) v += bf2f(lds[lrow * SK + c]) * sW3[c];
    v += __shfl_down(v, 2, 4);
    v += __shfl_down(v, 1, 4);
    if (t4 == 0 && lrow < cnt) logits[v0 + lrow] = v + b3[0];
}

// ---------------- loss ----------------
__device__ __forceinline__ float softplusf(float x) {
    return fmaxf(x, 0.f) + log1pf(expf(-fabsf(x)));
}

__global__ void k_loss(const float* __restrict__ logits, const int* __restrict__ lit_var,
                       const int* __restrict__ lit_neg, float* __restrict__ loss_acc,
                       int cpg) {
    const int g = blockIdx.x;
    const int tid = threadIdx.x;
    float part = 0.f;
    int cend = (g + 1) * cpg;
    for (int c = g * cpg + tid; c < cend; c += 256) {
        float cs = 0.f;
#pragma unroll
        for (int t = 0; t < 3; ++t) {
            int i = c * 3 + t;
            float sign = lit_neg[i] ? -1.f : 1.f;
            cs += softplusf(logits[lit_var[i]] * sign);
        }
        float vc = expf(-cs);
        part += vc * (-log1pf(LOSS_EPS - vc));
    }
    __shared__ float red[256];
    red[tid] = part;
    __syncthreads();
    for (int s = 128; s > 0; s >>= 1) {
        if (tid < s) red[tid] += red[tid + s];
        __syncthreads();
    }
    if (tid == 0) atomicAdd(loss_acc, sqrtf(red[0] + 1e-6f));
}

__global__ void k_output(float* __restrict__ dout, const float* __restrict__ logits,
                         const float* __restrict__ loss_acc, int nv) {
    int i = blockIdx.x * 256 + threadIdx.x;
    if (i < nv) dout[i] = logits[i];
    else if (i == nv) dout[i] = loss_acc[0] * (1.f / (float)NROUNDS);
}

// ---------------- host ----------------

extern "C" void kernel_launch(void* const* d_in, const int* in_sizes, int n_in,
                              void* d_out, int out_size, void* d_ws, size_t ws_size,
                              hipStream_t stream) {
    const int* lit_var    = (const int*)d_in[0];
    const int* lit_neg    = (const int*)d_in[1];
    const int* clause_idx = (const int*)d_in[2];
    const float* Lscale = (const float*)d_in[7];
    const float* Cscale = (const float*)d_in[8];
    const float* LCs    = (const float*)d_in[9];
    const float* CLs    = (const float*)d_in[10];
    const float* LuW0 = (const float*)d_in[11]; const float* Lub0 = (const float*)d_in[12];
    const float* LuW1 = (const float*)d_in[13]; const float* Lub1 = (const float*)d_in[14];
    const float* CuW0 = (const float*)d_in[15]; const float* Cub0 = (const float*)d_in[16];
    const float* CuW1 = (const float*)d_in[17]; const float* Cub1 = (const float*)d_in[18];
    const float* VsW0 = (const float*)d_in[19]; const float* Vsb0 = (const float*)d_in[20];
    const float* VsW1 = (const float*)d_in[21]; const float* Vsb1 = (const float*)d_in[22];
    const float* VsW2 = (const float*)d_in[23]; const float* Vsb2 = (const float*)d_in[24];
    const float* VsW3 = (const float*)d_in[25]; const float* Vsb3 = (const float*)d_in[26];

    const int ncell = in_sizes[0];          // 1,260,000
    const int ncl   = in_sizes[3];          // 420,000
    const int nv    = NV_CONST;
    const int nl    = 2 * nv;
    const int ng    = NG_CONST;

    size_t off = 0;
    auto A = [&](size_t bytes) -> void* {
        void* q = (char*)d_ws + off;
        off = (off + bytes + 255) & ~(size_t)255;
        return q;
    };
    short* Cb    = (short*)A((size_t)ncl * 80 * 2);    // raw C state (bf16, direct path)
    short* Lraw  = (short*)A((size_t)nl * 80 * 2);     // raw L state (bf16)
    short* Lb    = (short*)A((size_t)nv * 160 * 2);    // pre-normed L [v|v+nv] (bf16)
    short* CLb   = (short*)A((size_t)nl * 80 * 2);     // literal messages (bf16)
    unsigned char* Lb8 = (unsigned char*)A((size_t)nv * 160);  // fp8 pre-normed L (gather)
    unsigned char* Cb8 = (unsigned char*)A((size_t)ncl * 80);  // fp8 raw C (gather)
    float* logits = (float*)A((size_t)nv * 4);
    float* slabC  = (float*)A(33 * 160 * 4);
    float* slabL  = (float*)A(33 * 160 * 4);
    float* loss_a = (float*)A(256);
    int* litrow  = (int*)A((size_t)ncell * 4);
    int* lofs    = (int*)A((size_t)ncell * 4);
    int* row_ptr = (int*)A((size_t)(nl + 1) * 4);
    int* tmp     = (int*)A((size_t)nl * 4);
    int* cl_of   = (int*)A((size_t)ncell * 4);
    short* CuW0p = (short*)A((size_t)10 * 5 * 64 * 16);
    short* CuW1p = (short*)A((size_t)5  * 5 * 64 * 16);
    short* LuW0p = (short*)A((size_t)15 * 8 * 64 * 16);
    short* LuW1p = (short*)A((size_t)5  * 8 * 64 * 16);
    short* VsW0p = (short*)A((size_t)10 * 5 * 64 * 16);
    short* VsW1p = (short*)A((size_t)10 * 5 * 64 * 16);
    short* VsW2p = (short*)A((size_t)10 * 5 * 64 * 16);

    const dim3 B64x4(64, 4, 1);

    // ---- setup ----
    k_zero_i<<<(nl + 255) / 256, 256, 0, stream>>>(tmp, nl);
    k_init_slabs<<<(33 * 160 + 255) / 256, 256, 0, stream>>>(slabC, slabL, loss_a, (float)ncl);
    k_litrow<<<(ncell + 255) / 256, 256, 0, stream>>>(lit_var, lit_neg, litrow, lofs, tmp, ncell, nv);
    k_scan4<<<1, 1024, 0, stream>>>(tmp, row_ptr, nl, ncell);
    k_copy_int<<<(nl + 255) / 256, 256, 0, stream>>>(tmp, row_ptr, nl);
    k_fill_csr<<<(ncell + 255) / 256, 256, 0, stream>>>(litrow, clause_idx, tmp, cl_of, ncell);
    k_fill_b<<<(ncl * 80 + 255) / 256, 256, 0, stream>>>(Cb, ncl * 80, Cscale);
    k_fill_b<<<(nl * 80 + 255) / 256, 256, 0, stream>>>(Lraw, nl * 80, Lscale);
    k_fill_b<<<(nv * 160 + 255) / 256, 256, 0, stream>>>(Lb, nv * 160, Lscale);
    k_fill_q8<<<(nv * 160 + 255) / 256, 256, 0, stream>>>(Lb8, nv * 160, Lscale);
    k_fill_q8<<<(ncl * 80 + 255) / 256, 256, 0, stream>>>(Cb8, ncl * 80, Cscale);
    k_pack_w<<<(10 * 5 * 64 + 255) / 256, 256, 0, stream>>>(CuW0, CuW0p, 160, 160, 5, 10);
    k_pack_w<<<(5  * 5 * 64 + 255) / 256, 256, 0, stream>>>(CuW1, CuW1p, 160, 80, 5, 5);
    k_pack_w<<<(15 * 8 * 64 + 255) / 256, 256, 0, stream>>>(LuW0, LuW0p, 240, 240, 8, 15);
    k_pack_w<<<(5  * 8 * 64 + 255) / 256, 256, 0, stream>>>(LuW1, LuW1p, 240, 80, 8, 5);
    k_pack_w<<<(10 * 5 * 64 + 255) / 256, 256, 0, stream>>>(VsW0, VsW0p, 160, 160, 5, 10);
    k_pack_w<<<(10 * 5 * 64 + 255) / 256, 256, 0, stream>>>(VsW1, VsW1p, 160, 160, 5, 10);
    k_pack_w<<<(10 * 5 * 64 + 255) / 256, 256, 0, stream>>>(VsW2, VsW2p, 160, 160, 5, 10);

    const int cblk  = (ncl + 63) / 64;          // 6563
    const int lblk  = nv / 32;                  // 3125
    const int vblk  = (nv + 63) / 64;           // 1563
    const int clblk = (nl * 5 + 255) / 256;     // 3907
    const float MinvC = 1.f / (float)ncl;
    const float MinvL = 1.f / (float)nl;

    for (int r = 0; r < NROUNDS; ++r) {
        float* sCr  = slabC + (size_t)r * 160;        // stats of input C state
        float* sCr1 = slabC + (size_t)(r + 1) * 160;  // stats of new C (this round)
        float* sLr1 = slabL + (size_t)(r + 1) * 160;  // stats of new L (this round)
        k_c_update<<<cblk, B64x4, 0, stream>>>(
            Cb, Cb8, Lb8, lofs, LCs, (const short8*)CuW0p, Cub0, (const short8*)CuW1p, Cub1,
            sCr, sCr1, MinvC, ncl);
        k_cl_gather<<<clblk, 256, 0, stream>>>(Cb8, row_ptr, cl_of, CLs, sCr1, MinvC, CLb, nl);
        k_l_update<<<lblk, B64x4, 0, stream>>>(
            Lraw, Lb, CLb, (const short8*)LuW0p, Lub0, (const short8*)LuW1p, Lub1, sLr1, nv);
        k_v_head<<<vblk, B64x4, 0, stream>>>(
            Lraw, sLr1, MinvL, (const short8*)VsW0p, Vsb0, (const short8*)VsW1p, Vsb1,
            (const short8*)VsW2p, Vsb2, VsW3, Vsb3, logits, Lb, Lb8, nv);
        k_loss<<<ng, 256, 0, stream>>>(logits, lit_var, lit_neg, loss_a, ncl / ng);
    }

    k_output<<<(nv + 1 + 255) / 256, 256, 0, stream>>>((float*)d_out, logits, loss_a, nv);
}

// Round 16
// 15601.991 us; speedup vs baseline: 1.0085x; 1.0085x over previous
//
#include <hip/hip_runtime.h>
#include <hip/hip_fp8.h>
#include <math.h>

// SimpleNeuroSAT on MI355X — round 15 (final): exact round-13 configuration,
// the measured optimum (15.68ms). Round-14's LDS-lofs staging + SK padding were
// neutral (216 vs 212µs, conflicts up) and are dropped.
// Converged structure: fused MFMA MLP kernels (c_update / l_update / v_head),
// standalone high-TLP CL gather, bf16 state + fp8-e4m3 gather sources (16B
// chunks), round-indexed stat slabs, CSR built once per launch.
// Remaining cost is the L3-resident random-gather latency floor (~490µs/round,
// ~1.3TB/s effective); all structural variants measured neutral or worse
// (rounds 5, 8, 9, 11, 14).

#define NROUNDS 32
#define NORM_EPS 1e-3f
#define LOSS_EPS 1e-8f

static constexpr int NV_CONST = 100000;
static constexpr int NG_CONST = 100;

typedef __attribute__((ext_vector_type(8))) short short8;
typedef __attribute__((ext_vector_type(8))) unsigned char uchar8;
typedef __attribute__((ext_vector_type(16))) unsigned char uchar16;
typedef __attribute__((ext_vector_type(4))) float f32x4;

__device__ __forceinline__ short f2bf(float f) {
    union { float f; unsigned u; } x; x.f = f;
    unsigned r = x.u + 0x7fffu + ((x.u >> 16) & 1u);   // RNE
    return (short)(r >> 16);
}
__device__ __forceinline__ float bf2f(short s) {
    union { unsigned u; float f; } x; x.u = ((unsigned)(unsigned short)s) << 16;
    return x.f;
}
__device__ __forceinline__ unsigned char f2q8(float f) {
    f = fminf(fmaxf(f, -448.f), 448.f);    // e4m3fn finite range
    __hip_fp8_e4m3 t(f);
    return t.__x;
}
__device__ __forceinline__ float q82f(unsigned char b) {
    __hip_fp8_e4m3 t; t.__x = b;
    return (float)t;
}

// ---------------- setup kernels ----------------

__global__ void k_zero_i(int* __restrict__ p, int n) {
    int i = blockIdx.x * 256 + threadIdx.x;
    if (i < n) p[i] = 0;
}
__global__ void k_fill_b(short* __restrict__ p, int n, const float* __restrict__ vp) {
    int i = blockIdx.x * 256 + threadIdx.x;
    if (i < n) p[i] = f2bf(*vp);
}
__global__ void k_fill_q8(unsigned char* __restrict__ p, int n, const float* __restrict__ vp) {
    int i = blockIdx.x * 256 + threadIdx.x;
    if (i < n) p[i] = f2q8(*vp);
}
__global__ void k_copy_int(int* __restrict__ dst, const int* __restrict__ src, int n) {
    int i = blockIdx.x * 256 + threadIdx.x;
    if (i < n) dst[i] = src[i];
}
// zero all slabs; slabC[0] = identity (mean 0, E[x^2]=ncl*(1-eps) so rstd==1 exactly)
__global__ void k_init_slabs(float* __restrict__ slabC, float* __restrict__ slabL,
                             float* __restrict__ loss_a, float nclf) {
    int i = blockIdx.x * 256 + threadIdx.x;
    if (i < 33 * 160) {
        slabC[i] = (i >= 80 && i < 160) ? nclf * (1.f - NORM_EPS) : 0.f;
        slabL[i] = 0.f;
    }
    if (i == 0) loss_a[0] = 0.f;
}

// litrow for CSR build + static chunk-offsets (8-elem units; always even, so
// the 16-elem uchar16 offset is lofs>>1)
__global__ void k_litrow(const int* __restrict__ lit_var, const int* __restrict__ lit_neg,
                         int* __restrict__ litrow, int* __restrict__ lofs,
                         int* __restrict__ counts, int ncell, int nv) {
    int i = blockIdx.x * 256 + threadIdx.x;
    if (i < ncell) {
        int r = lit_var[i] + lit_neg[i] * nv;
        litrow[i] = r;
        lofs[i] = (r < nv) ? r * 20 : (r - nv) * 20 + 10;
        atomicAdd(&counts[r], 1);
    }
}

__launch_bounds__(1024)
__global__ void k_scan4(const int* __restrict__ counts, int* __restrict__ row_ptr,
                        int n, int total) {
    __shared__ int sd[1024];
    __shared__ int carry;
    int tid = threadIdx.x;
    if (tid == 0) carry = 0;
    __syncthreads();
    for (int base = 0; base < n; base += 4096) {
        int i0 = base + tid * 4;
        int a0 = (i0 + 0 < n) ? counts[i0 + 0] : 0;
        int a1 = (i0 + 1 < n) ? counts[i0 + 1] : 0;
        int a2 = (i0 + 2 < n) ? counts[i0 + 2] : 0;
        int a3 = (i0 + 3 < n) ? counts[i0 + 3] : 0;
        int s = a0 + a1 + a2 + a3;
        sd[tid] = s;
        __syncthreads();
        for (int off = 1; off < 1024; off <<= 1) {
            int t = (tid >= off) ? sd[tid - off] : 0;
            __syncthreads();
            sd[tid] += t;
            __syncthreads();
        }
        int excl = carry + sd[tid] - s;
        if (i0 + 0 < n) row_ptr[i0 + 0] = excl;
        if (i0 + 1 < n) row_ptr[i0 + 1] = excl + a0;
        if (i0 + 2 < n) row_ptr[i0 + 2] = excl + a0 + a1;
        if (i0 + 3 < n) row_ptr[i0 + 3] = excl + a0 + a1 + a2;
        __syncthreads();
        if (tid == 0) carry += sd[1023];
        __syncthreads();
    }
    if (tid == 0) row_ptr[n] = total;
}

__global__ void k_fill_csr(const int* __restrict__ litrow, const int* __restrict__ clause_idx,
                           int* __restrict__ cursor, int* __restrict__ cl_of, int ncell) {
    int i = blockIdx.x * 256 + threadIdx.x;
    if (i < ncell) {
        int r = litrow[i];
        int pos = atomicAdd(&cursor[r], 1);
        cl_of[pos] = clause_idx[i];
    }
}

// Wp frag t=(nb*KB+kb)*64+lane holds W[kb*32+quad*8+j][nb*16+(lane&15)], zero-padded.
__global__ void k_pack_w(const float* __restrict__ W, short* __restrict__ Wp,
                         int K, int N, int KB, int NB) {
    int t = blockIdx.x * 256 + threadIdx.x;
    int tot = NB * KB * 64;
    if (t >= tot) return;
    int lane = t & 63;
    int kb = (t >> 6) % KB;
    int nb = t / (64 * KB);
    int quad = lane >> 4, l15 = lane & 15;
    int n = nb * 16 + l15;
#pragma unroll
    for (int j = 0; j < 8; ++j) {
        int k = kb * 32 + quad * 8 + j;
        float f = (k < K && n < N) ? W[(size_t)k * N + n] : 0.f;
        Wp[(size_t)t * 8 + j] = f2bf(f);
    }
}

// ---------------- MFMA building blocks ----------------

template <int KB, int NB>
__device__ __forceinline__ void mfma_layer(const short* lds, int SK,
                                           const short8* __restrict__ Wp,
                                           f32x4* acc, int lane, int arow) {
    const int quad8 = (lane >> 4) * 8;
    short8 a[KB];
#pragma unroll
    for (int kb = 0; kb < KB; ++kb)
        a[kb] = *(const short8*)(lds + arow * SK + kb * 32 + quad8);
#pragma unroll
    for (int kb = 0; kb < KB; ++kb)
#pragma unroll
        for (int nb = 0; nb < NB; ++nb)
            acc[nb] = __builtin_amdgcn_mfma_f32_16x16x32_bf16(
                a[kb], Wp[(nb * KB + kb) * 64 + lane], acc[nb], 0, 0, 0);
}

// wave-private: writes only rows wr0..wr0+15 (same stripe the wave reads)
template <int NB>
__device__ __forceinline__ void write_hidden(short* ldsH, int SKH, const f32x4* acc,
                                             const float* __restrict__ bias,
                                             int l15, int quad, int wr0) {
#pragma unroll
    for (int nb = 0; nb < NB; ++nb) {
        int c = nb * 16 + l15;
        float bv = bias[c];
#pragma unroll
        for (int reg = 0; reg < 4; ++reg) {
            int row = wr0 + quad * 4 + reg;
            float v = acc[nb][reg] + bv;
            v = fminf(fmaxf(v, 0.f), 6.f);
            ldsH[row * SKH + c] = f2bf(v);
        }
    }
}

// compute mean/rstd from an accum slab into shared sS[160] (callers sync after)
__device__ __forceinline__ void load_stats(const float* __restrict__ slab, float Minv,
                                           float* sS, int tid) {
    if (tid < 80) {
        float m = slab[tid] * Minv;
        float v = slab[80 + tid] * Minv - m * m;
        sS[tid] = m;
        sS[80 + tid] = rsqrtf(v + NORM_EPS);
    }
}

// ---------------- fused C update (16B fp8 LC gather) ----------------
__launch_bounds__(256, 2)
__global__ void k_c_update(short* __restrict__ Cb, unsigned char* __restrict__ Cb8,
                           const unsigned char* __restrict__ Lb8,
                           const int* __restrict__ lofs, const float* __restrict__ scp,
                           const short8* __restrict__ W0p, const float* __restrict__ b0,
                           const short8* __restrict__ W1p, const float* __restrict__ b1,
                           const float* __restrict__ prevSlab, float* __restrict__ nextSlab,
                           float Minv, int ncl) {
    constexpr int SK = 168;
    __shared__ short lds[64 * SK];
    __shared__ float sred[160], sC[160];
    const int lane = threadIdx.x, wy = threadIdx.y, tid = wy * 64 + lane;
    const int r0 = blockIdx.x * 64;
    const int rows = (ncl - r0 < 64) ? (ncl - r0) : 64;

    if (tid < 160) sred[tid] = 0.f;
    load_stats(prevSlab, Minv, sC, tid);
    __syncthreads();

    const float s = *scp;
    const short8* Cbv = (const short8*)Cb;
    const uchar16* Lq = (const uchar16*)Lb8;
    // 15 items/row: 10 direct bf16 8-elem chunks + 5 gather fp8 16-elem chunks.
    // Independent iterations — compiler overlaps loads (round-10-verified structure).
    // Lanes covering one clause's 5 chunks are consecutive -> HW-coalesced sectors.
    for (int it = tid; it < 64 * 15; it += 256) {
        int lr = it / 15, c = it - lr * 15;
        int cl = r0 + ((lr < rows) ? lr : rows - 1);
        if (c < 10) {
            short8 v = Cbv[(size_t)cl * 10 + c];
            int col = c * 8;
            short8 o;
#pragma unroll
            for (int j = 0; j < 8; ++j)
                o[j] = f2bf((bf2f(v[j]) - sC[col + j]) * sC[80 + col + j]);
            *(short8*)(lds + lr * SK + col) = o;
        } else {
            int cc = c - 10, b = cl * 3;           // cc: 16-elem chunk 0..4
            int oa = lofs[b] >> 1, ob = lofs[b + 1] >> 1, oc = lofs[b + 2] >> 1;
            uchar16 va = Lq[(size_t)oa + cc];
            uchar16 vb = Lq[(size_t)ob + cc];
            uchar16 vc = Lq[(size_t)oc + cc];
            short8 o0, o1;
#pragma unroll
            for (int j = 0; j < 8; ++j) {
                o0[j] = f2bf((q82f(va[j]) + q82f(vb[j]) + q82f(vc[j])) * s);
                o1[j] = f2bf((q82f(va[8 + j]) + q82f(vb[8 + j]) + q82f(vc[8 + j])) * s);
            }
            *(short8*)(lds + lr * SK + 80 + cc * 16) = o0;
            *(short8*)(lds + lr * SK + 80 + cc * 16 + 8) = o1;
        }
    }
    __syncthreads();   // staging crosses stripes; everything after is wave-private

    const int quad = lane >> 4, l15 = lane & 15, wr0 = wy * 16, arow = wr0 + l15;

    f32x4 acc[10];
#pragma unroll
    for (int nb = 0; nb < 10; ++nb) { f32x4 z = {0.f, 0.f, 0.f, 0.f}; acc[nb] = z; }
    mfma_layer<5, 10>(lds, SK, W0p, acc, lane, arow);
    write_hidden<10>(lds, SK, acc, b0, l15, quad, wr0);

    f32x4 acc2[5];
#pragma unroll
    for (int nb = 0; nb < 5; ++nb) { f32x4 z = {0.f, 0.f, 0.f, 0.f}; acc2[nb] = z; }
    mfma_layer<5, 5>(lds, SK, W1p, acc2, lane, arow);

#pragma unroll
    for (int nb = 0; nb < 5; ++nb) {
        int cc = nb * 16 + l15;
        float bv = b1[cc];
        float s1 = 0.f, s2 = 0.f;
#pragma unroll
        for (int reg = 0; reg < 4; ++reg) {
            int lr = wr0 + quad * 4 + reg;
            if (lr < rows) {
                float v = acc2[nb][reg] + bv;
                Cb[(size_t)(r0 + lr) * 80 + cc] = f2bf(v);
                Cb8[(size_t)(r0 + lr) * 80 + cc] = f2q8(v);
                s1 += v; s2 += v * v;
            }
        }
        s1 += __shfl_xor(s1, 16); s1 += __shfl_xor(s1, 32);
        s2 += __shfl_xor(s2, 16); s2 += __shfl_xor(s2, 32);
        if (quad == 0) { atomicAdd(&sred[cc], s1); atomicAdd(&sred[80 + cc], s2); }
    }
    __syncthreads();
    if (tid < 160) atomicAdd(&nextSlab[tid], sred[tid]);
}

// ---------------- standalone CL gather (fp8 source, 16B chunks, 4-unroll) ----------------
// thread = (literal row, 16-elem chunk of 5). Writes CLb = normalized bf16 message.
__launch_bounds__(256)
__global__ void k_cl_gather(const unsigned char* __restrict__ Cb8,
                            const int* __restrict__ row_ptr,
                            const int* __restrict__ cl_of, const float* __restrict__ scp,
                            const float* __restrict__ slab, float Minv,
                            short* __restrict__ CLb, int nl) {
    __shared__ float sC[160];
    load_stats(slab, Minv, sC, threadIdx.x);
    __syncthreads();
    int idx = blockIdx.x * 256 + threadIdx.x;
    if (idx >= nl * 5) return;
    int r = idx / 5, c16 = idx - r * 5;
    int p0 = row_ptr[r], p1 = row_ptr[r + 1];
    float a[16];
#pragma unroll
    for (int j = 0; j < 16; ++j) a[j] = 0.f;
    const uchar16* Cq = (const uchar16*)Cb8;
    int p = p0;
    for (; p + 4 <= p1; p += 4) {
        int i0 = cl_of[p], i1 = cl_of[p + 1], i2 = cl_of[p + 2], i3 = cl_of[p + 3];
        uchar16 v0 = Cq[(size_t)i0 * 5 + c16];
        uchar16 v1 = Cq[(size_t)i1 * 5 + c16];
        uchar16 v2 = Cq[(size_t)i2 * 5 + c16];
        uchar16 v3 = Cq[(size_t)i3 * 5 + c16];
#pragma unroll
        for (int j = 0; j < 16; ++j)
            a[j] += (q82f(v0[j]) + q82f(v1[j])) + (q82f(v2[j]) + q82f(v3[j]));
    }
    for (; p < p1; ++p) {
        uchar16 v = Cq[(size_t)cl_of[p] * 5 + c16];
#pragma unroll
        for (int j = 0; j < 16; ++j) a[j] += q82f(v[j]);
    }
    float n = (float)(p1 - p0), s = *scp;
    int col = c16 * 16;
    short8 o0, o1;
#pragma unroll
    for (int j = 0; j < 8; ++j) {
        o0[j] = f2bf((a[j] - n * sC[col + j]) * sC[80 + col + j] * s);
        o1[j] = f2bf((a[8 + j] - n * sC[col + 8 + j]) * sC[80 + col + 8 + j] * s);
    }
    ((short8*)CLb)[(size_t)r * 10 + c16 * 2] = o0;
    ((short8*)CLb)[(size_t)r * 10 + c16 * 2 + 1] = o1;
}

// ---------------- fused L update (pure streaming, ILP staging) ----------------
// paired rows [vb,vb+32) u [vb+nv,vb+nv+32); writes Lraw bf16 + accumL slab.
__launch_bounds__(256, 2)
__global__ void k_l_update(short* __restrict__ Lraw, const short* __restrict__ Lb,
                           const short* __restrict__ CLb,
                           const short8* __restrict__ W0p, const float* __restrict__ b0,
                           const short8* __restrict__ W1p, const float* __restrict__ b1,
                           float* __restrict__ nextSlab, int nv) {
    constexpr int SK = 264;
    __shared__ short lds[64 * SK];             // input K=256, then hidden 240+16pad
    __shared__ float sred[160];
    const int lane = threadIdx.x, wy = threadIdx.y, tid = wy * 64 + lane;
    const int vb = blockIdx.x * 32;

    if (tid < 160) sred[tid] = 0.f;
    __syncthreads();

    const short8* Lb8  = (const short8*)Lb;
    const short8* CLb8 = (const short8*)CLb;
    short8 vals[8];
#pragma unroll
    for (int u = 0; u < 8; ++u) {
        int it = tid + u * 256;
        int lr = it >> 5, c = it & 31;
        int v = (lr < 32) ? vb + lr : vb + (lr - 32);
        int half0 = (lr < 32) ? 0 : 10;
        if (c < 10) {
            vals[u] = Lb8[(size_t)v * 20 + half0 + c];
        } else if (c < 20) {
            int r = (lr < 32) ? vb + lr : vb + nv + (lr - 32);
            vals[u] = CLb8[(size_t)r * 10 + (c - 10)];
        } else if (c < 30) {
            vals[u] = Lb8[(size_t)v * 20 + (10 - half0) + (c - 20)];
        } else {
            short8 z = {0, 0, 0, 0, 0, 0, 0, 0};
            vals[u] = z;
        }
    }
#pragma unroll
    for (int u = 0; u < 8; ++u) {
        int it = tid + u * 256;
        int lr = it >> 5, c = it & 31;
        int o = (c < 10) ? c * 8 : (c < 20) ? 80 + (c - 10) * 8
              : (c < 30) ? 160 + (c - 20) * 8 : 240 + (c - 30) * 8;
        *(short8*)(lds + lr * SK + o) = vals[u];
    }
    __syncthreads();   // staging crosses stripes; rest is wave-private

    const int quad = lane >> 4, l15 = lane & 15, wr0 = wy * 16, arow = wr0 + l15;

    f32x4 acc[15];
#pragma unroll
    for (int nb = 0; nb < 15; ++nb) { f32x4 z = {0.f, 0.f, 0.f, 0.f}; acc[nb] = z; }
    mfma_layer<8, 15>(lds, SK, W0p, acc, lane, arow);
    write_hidden<15>(lds, SK, acc, b0, l15, quad, wr0);
    {   // zero-pad hidden cols 240..255 of OWN stripe (wave-private)
        int row = wr0 + (lane >> 2);
        int c = 240 + (lane & 3) * 4;
        short4 z; z.x = 0; z.y = 0; z.z = 0; z.w = 0;
        *(short4*)(lds + row * SK + c) = z;
    }

    f32x4 acc2[5];
#pragma unroll
    for (int nb = 0; nb < 5; ++nb) { f32x4 z = {0.f, 0.f, 0.f, 0.f}; acc2[nb] = z; }
    mfma_layer<8, 5>(lds, SK, W1p, acc2, lane, arow);

#pragma unroll
    for (int nb = 0; nb < 5; ++nb) {
        int cc = nb * 16 + l15;
        float bv = b1[cc];
        float s1 = 0.f, s2 = 0.f;
#pragma unroll
        for (int reg = 0; reg < 4; ++reg) {
            int lr = wr0 + quad * 4 + reg;
            int rabs = (lr < 32) ? vb + lr : vb + nv + (lr - 32);
            float v = acc2[nb][reg] + bv;
            Lraw[(size_t)rabs * 80 + cc] = f2bf(v);
            s1 += v; s2 += v * v;
        }
        s1 += __shfl_xor(s1, 16); s1 += __shfl_xor(s1, 32);
        s2 += __shfl_xor(s2, 16); s2 += __shfl_xor(s2, 32);
        if (quad == 0) { atomicAdd(&sred[cc], s1); atomicAdd(&sred[80 + cc], s2); }
    }
    __syncthreads();
    if (tid < 160) atomicAdd(&nextSlab[tid], sred[tid]);
}

// ---------------- fused V head (4 layers; emits Lb bf16 + Lb8 fp8) ----------------
__launch_bounds__(256, 2)
__global__ void k_v_head(const short* __restrict__ Lraw, const float* __restrict__ slab,
                         float Minv,
                         const short8* __restrict__ W0p, const float* __restrict__ b0,
                         const short8* __restrict__ W1p, const float* __restrict__ b1,
                         const short8* __restrict__ W2p, const float* __restrict__ b2,
                         const float* __restrict__ W3, const float* __restrict__ b3,
                         float* __restrict__ logits, short* __restrict__ Lb,
                         unsigned char* __restrict__ Lb8, int nv) {
    constexpr int SK = 168;
    __shared__ short lds[64 * SK];
    __shared__ float sW3[160], sL[160];
    const int lane = threadIdx.x, wy = threadIdx.y, tid = wy * 64 + lane;
    const int v0 = blockIdx.x * 64;
    const int cnt = (nv - v0 < 64) ? (nv - v0) : 64;

    if (tid < 160) sW3[tid] = W3[tid];
    load_stats(slab, Minv, sL, tid);
    __syncthreads();

    const short8* Lraw8 = (const short8*)Lraw;
    short8 vals[5];
#pragma unroll
    for (int u = 0; u < 5; ++u) {
        int it = tid + u * 256;
        int lr = it / 20, c = it - lr * 20;
        int v = v0 + ((lr < cnt) ? lr : cnt - 1);
        int row = (c < 10) ? v : v + nv;
        int cc = (c < 10) ? c : c - 10;
        vals[u] = Lraw8[(size_t)row * 10 + cc];
    }
#pragma unroll
    for (int u = 0; u < 5; ++u) {
        int it = tid + u * 256;
        int lr = it / 20, c = it - lr * 20;
        int v = v0 + ((lr < cnt) ? lr : cnt - 1);
        int cc = (c < 10) ? c : c - 10;
        int col = cc * 8;
        short8 o;
        uchar8 q;
#pragma unroll
        for (int j = 0; j < 8; ++j) {
            float f = (bf2f(vals[u][j]) - sL[col + j]) * sL[80 + col + j];
            o[j] = f2bf(f);
            q[j] = f2q8(f);
        }
        *(short8*)(lds + lr * SK + c * 8) = o;
        if (lr < cnt) {
            *(short8*)(Lb + (size_t)v * 160 + c * 8) = o;
            *(uchar8*)(Lb8 + (size_t)v * 160 + c * 8) = q;
        }
    }
    __syncthreads();   // staging crosses stripes

    const int quad = lane >> 4, l15 = lane & 15, wr0 = wy * 16, arow = wr0 + l15;

    f32x4 acc[10];
#pragma unroll
    for (int nb = 0; nb < 10; ++nb) { f32x4 z = {0.f, 0.f, 0.f, 0.f}; acc[nb] = z; }
    mfma_layer<5, 10>(lds, SK, W0p, acc, lane, arow);
    write_hidden<10>(lds, SK, acc, b0, l15, quad, wr0);

#pragma unroll
    for (int nb = 0; nb < 10; ++nb) { f32x4 z = {0.f, 0.f, 0.f, 0.f}; acc[nb] = z; }
    mfma_layer<5, 10>(lds, SK, W1p, acc, lane, arow);
    write_hidden<10>(lds, SK, acc, b1, l15, quad, wr0);

#pragma unroll
    for (int nb = 0; nb < 10; ++nb) { f32x4 z = {0.f, 0.f, 0.f, 0.f}; acc[nb] = z; }
    mfma_layer<5, 10>(lds, SK, W2p, acc, lane, arow);
    write_hidden<10>(lds, SK, acc, b2, l15, quad, wr0);
    __syncthreads();   // final dot reads across stripes

    int lrow = tid >> 2, t4 = tid & 3;
    float v = 0.f;
    for (int c = t4; c < 160; c += 4) v += bf2f(lds[lrow * SK + c]) * sW3[c];
    v += __shfl_down(v, 2, 4);
    v += __shfl_down(v, 1, 4);
    if (t4 == 0 && lrow < cnt) logits[v0 + lrow] = v + b3[0];
}

// ---------------- loss ----------------
__device__ __forceinline__ float softplusf(float x) {
    return fmaxf(x, 0.f) + log1pf(expf(-fabsf(x)));
}

__global__ void k_loss(const float* __restrict__ logits, const int* __restrict__ lit_var,
                       const int* __restrict__ lit_neg, float* __restrict__ loss_acc,
                       int cpg) {
    const int g = blockIdx.x;
    const int tid = threadIdx.x;
    float part = 0.f;
    int cend = (g + 1) * cpg;
    for (int c = g * cpg + tid; c < cend; c += 256) {
        float cs = 0.f;
#pragma unroll
        for (int t = 0; t < 3; ++t) {
            int i = c * 3 + t;
            float sign = lit_neg[i] ? -1.f : 1.f;
            cs += softplusf(logits[lit_var[i]] * sign);
        }
        float vc = expf(-cs);
        part += vc * (-log1pf(LOSS_EPS - vc));
    }
    __shared__ float red[256];
    red[tid] = part;
    __syncthreads();
    for (int s = 128; s > 0; s >>= 1) {
        if (tid < s) red[tid] += red[tid + s];
        __syncthreads();
    }
    if (tid == 0) atomicAdd(loss_acc, sqrtf(red[0] + 1e-6f));
}

__global__ void k_output(float* __restrict__ dout, const float* __restrict__ logits,
                         const float* __restrict__ loss_acc, int nv) {
    int i = blockIdx.x * 256 + threadIdx.x;
    if (i < nv) dout[i] = logits[i];
    else if (i == nv) dout[i] = loss_acc[0] * (1.f / (float)NROUNDS);
}

// ---------------- host ----------------

extern "C" void kernel_launch(void* const* d_in, const int* in_sizes, int n_in,
                              void* d_out, int out_size, void* d_ws, size_t ws_size,
                              hipStream_t stream) {
    const int* lit_var    = (const int*)d_in[0];
    const int* lit_neg    = (const int*)d_in[1];
    const int* clause_idx = (const int*)d_in[2];
    const float* Lscale = (const float*)d_in[7];
    const float* Cscale = (const float*)d_in[8];
    const float* LCs    = (const float*)d_in[9];
    const float* CLs    = (const float*)d_in[10];
    const float* LuW0 = (const float*)d_in[11]; const float* Lub0 = (const float*)d_in[12];
    const float* LuW1 = (const float*)d_in[13]; const float* Lub1 = (const float*)d_in[14];
    const float* CuW0 = (const float*)d_in[15]; const float* Cub0 = (const float*)d_in[16];
    const float* CuW1 = (const float*)d_in[17]; const float* Cub1 = (const float*)d_in[18];
    const float* VsW0 = (const float*)d_in[19]; const float* Vsb0 = (const float*)d_in[20];
    const float* VsW1 = (const float*)d_in[21]; const float* Vsb1 = (const float*)d_in[22];
    const float* VsW2 = (const float*)d_in[23]; const float* Vsb2 = (const float*)d_in[24];
    const float* VsW3 = (const float*)d_in[25]; const float* Vsb3 = (const float*)d_in[26];

    const int ncell = in_sizes[0];          // 1,260,000
    const int ncl   = in_sizes[3];          // 420,000
    const int nv    = NV_CONST;
    const int nl    = 2 * nv;
    const int ng    = NG_CONST;

    size_t off = 0;
    auto A = [&](size_t bytes) -> void* {
        void* q = (char*)d_ws + off;
        off = (off + bytes + 255) & ~(size_t)255;
        return q;
    };
    short* Cb    = (short*)A((size_t)ncl * 80 * 2);    // raw C state (bf16, direct path)
    short* Lraw  = (short*)A((size_t)nl * 80 * 2);     // raw L state (bf16)
    short* Lb    = (short*)A((size_t)nv * 160 * 2);    // pre-normed L [v|v+nv] (bf16)
    short* CLb   = (short*)A((size_t)nl * 80 * 2);     // literal messages (bf16)
    unsigned char* Lb8 = (unsigned char*)A((size_t)nv * 160);  // fp8 pre-normed L (gather)
    unsigned char* Cb8 = (unsigned char*)A((size_t)ncl * 80);  // fp8 raw C (gather)
    float* logits = (float*)A((size_t)nv * 4);
    float* slabC  = (float*)A(33 * 160 * 4);
    float* slabL  = (float*)A(33 * 160 * 4);
    float* loss_a = (float*)A(256);
    int* litrow  = (int*)A((size_t)ncell * 4);
    int* lofs    = (int*)A((size_t)ncell * 4);
    int* row_ptr = (int*)A((size_t)(nl + 1) * 4);
    int* tmp     = (int*)A((size_t)nl * 4);
    int* cl_of   = (int*)A((size_t)ncell * 4);
    short* CuW0p = (short*)A((size_t)10 * 5 * 64 * 16);
    short* CuW1p = (short*)A((size_t)5  * 5 * 64 * 16);
    short* LuW0p = (short*)A((size_t)15 * 8 * 64 * 16);
    short* LuW1p = (short*)A((size_t)5  * 8 * 64 * 16);
    short* VsW0p = (short*)A((size_t)10 * 5 * 64 * 16);
    short* VsW1p = (short*)A((size_t)10 * 5 * 64 * 16);
    short* VsW2p = (short*)A((size_t)10 * 5 * 64 * 16);

    const dim3 B64x4(64, 4, 1);

    // ---- setup ----
    k_zero_i<<<(nl + 255) / 256, 256, 0, stream>>>(tmp, nl);
    k_init_slabs<<<(33 * 160 + 255) / 256, 256, 0, stream>>>(slabC, slabL, loss_a, (float)ncl);
    k_litrow<<<(ncell + 255) / 256, 256, 0, stream>>>(lit_var, lit_neg, litrow, lofs, tmp, ncell, nv);
    k_scan4<<<1, 1024, 0, stream>>>(tmp, row_ptr, nl, ncell);
    k_copy_int<<<(nl + 255) / 256, 256, 0, stream>>>(tmp, row_ptr, nl);
    k_fill_csr<<<(ncell + 255) / 256, 256, 0, stream>>>(litrow, clause_idx, tmp, cl_of, ncell);
    k_fill_b<<<(ncl * 80 + 255) / 256, 256, 0, stream>>>(Cb, ncl * 80, Cscale);
    k_fill_b<<<(nl * 80 + 255) / 256, 256, 0, stream>>>(Lraw, nl * 80, Lscale);
    k_fill_b<<<(nv * 160 + 255) / 256, 256, 0, stream>>>(Lb, nv * 160, Lscale);
    k_fill_q8<<<(nv * 160 + 255) / 256, 256, 0, stream>>>(Lb8, nv * 160, Lscale);
    k_fill_q8<<<(ncl * 80 + 255) / 256, 256, 0, stream>>>(Cb8, ncl * 80, Cscale);
    k_pack_w<<<(10 * 5 * 64 + 255) / 256, 256, 0, stream>>>(CuW0, CuW0p, 160, 160, 5, 10);
    k_pack_w<<<(5  * 5 * 64 + 255) / 256, 256, 0, stream>>>(CuW1, CuW1p, 160, 80, 5, 5);
    k_pack_w<<<(15 * 8 * 64 + 255) / 256, 256, 0, stream>>>(LuW0, LuW0p, 240, 240, 8, 15);
    k_pack_w<<<(5  * 8 * 64 + 255) / 256, 256, 0, stream>>>(LuW1, LuW1p, 240, 80, 8, 5);
    k_pack_w<<<(10 * 5 * 64 + 255) / 256, 256, 0, stream>>>(VsW0, VsW0p, 160, 160, 5, 10);
    k_pack_w<<<(10 * 5 * 64 + 255) / 256, 256, 0, stream>>>(VsW1, VsW1p, 160, 160, 5, 10);
    k_pack_w<<<(10 * 5 * 64 + 255) / 256, 256, 0, stream>>>(VsW2, VsW2p, 160, 160, 5, 10);

    const int cblk  = (ncl + 63) / 64;          // 6563
    const int lblk  = nv / 32;                  // 3125
    const int vblk  = (nv + 63) / 64;           // 1563
    const int clblk = (nl * 5 + 255) / 256;     // 3907
    const float MinvC = 1.f / (float)ncl;
    const float MinvL = 1.f / (float)nl;

    for (int r = 0; r < NROUNDS; ++r) {
        float* sCr  = slabC + (size_t)r * 160;        // stats of input C state
        float* sCr1 = slabC + (size_t)(r + 1) * 160;  // stats of new C (this round)
        float* sLr1 = slabL + (size_t)(r + 1) * 160;  // stats of new L (this round)
        k_c_update<<<cblk, B64x4, 0, stream>>>(
            Cb, Cb8, Lb8, lofs, LCs, (const short8*)CuW0p, Cub0, (const short8*)CuW1p, Cub1,
            sCr, sCr1, MinvC, ncl);
        k_cl_gather<<<clblk, 256, 0, stream>>>(Cb8, row_ptr, cl_of, CLs, sCr1, MinvC, CLb, nl);
        k_l_update<<<lblk, B64x4, 0, stream>>>(
            Lraw, Lb, CLb, (const short8*)LuW0p, Lub0, (const short8*)LuW1p, Lub1, sLr1, nv);
        k_v_head<<<vblk, B64x4, 0, stream>>>(
            Lraw, sLr1, MinvL, (const short8*)VsW0p, Vsb0, (const short8*)VsW1p, Vsb1,
            (const short8*)VsW2p, Vsb2, VsW3, Vsb3, logits, Lb, Lb8, nv);
        k_loss<<<ng, 256, 0, stream>>>(logits, lit_var, lit_neg, loss_a, ncl / ng);
    }

    k_output<<<(nv + 1 + 255) / 256, 256, 0, stream>>>((float*)d_out, logits, loss_a, nv);
}